// Round 4
// baseline (1381.807 us; speedup 1.0000x reference)
//
#include <hip/hip_runtime.h>

#define NN 500000
#define SH 9
#define NPB 512                          // nodes per bucket (1 << SH)
#define NBUCK ((NN + NPB - 1) / NPB)     // 977
#define PT_TILE 32768                    // edges per partition block

typedef _Float16 hf4 __attribute__((ext_vector_type(4)));
typedef _Float16 hf2 __attribute__((ext_vector_type(2)));

// ============================================================================
// Bucketed GCN, half-precision gather tables:
//  1) k_bhist : per-bucket edge counts (LDS hist)
//  2) k_bscan : exclusive scan of 977 bucket counts -> bbase, cur
//  3) k_part  : partition edges; packed = (src<<9)|(dst&511), chunked writes
//  4) k_deg   : per-bucket LDS node counts -> dis = rsqrt(deg+1)
//  5) k_xw    : g1 = half4( dis * (x @ W1) )
//  6) k_agg*  : per-bucket LDS SoA accumulation of half gathers + fused
//               epilogue h = tanh(dis*(acc+g_self)+b); g_next = half(dis*(h@W))
// ============================================================================

__global__ __launch_bounds__(256) void k_bhist(const int* __restrict__ dst,
                                               int* __restrict__ bcount, int ne) {
    __shared__ int lh[NBUCK];
    for (int i = threadIdx.x; i < NBUCK; i += 256) lh[i] = 0;
    __syncthreads();
    int ne4 = ne >> 2;
    for (int i = blockIdx.x * 256 + threadIdx.x; i < ne4; i += gridDim.x * 256) {
        int4 d = ((const int4*)dst)[i];
        atomicAdd(&lh[d.x >> SH], 1);
        atomicAdd(&lh[d.y >> SH], 1);
        atomicAdd(&lh[d.z >> SH], 1);
        atomicAdd(&lh[d.w >> SH], 1);
    }
    if (blockIdx.x == 0) {
        for (int k = (ne & ~3) + threadIdx.x; k < ne; k += 256)
            atomicAdd(&lh[dst[k] >> SH], 1);
    }
    __syncthreads();
    for (int i = threadIdx.x; i < NBUCK; i += 256)
        if (lh[i]) atomicAdd(&bcount[i], lh[i]);
}

__global__ __launch_bounds__(1024) void k_bscan(const int* __restrict__ bcount,
                                                int* __restrict__ bbase,
                                                int* __restrict__ cur) {
    __shared__ int sh[1024];
    int t = threadIdx.x;
    int v = (t < NBUCK) ? bcount[t] : 0;
    sh[t] = v;
    __syncthreads();
    for (int o = 1; o < 1024; o <<= 1) {
        int a = (t >= o) ? sh[t - o] : 0;
        __syncthreads();
        sh[t] += a;
        __syncthreads();
    }
    if (t < NBUCK) {
        int excl = sh[t] - v;
        bbase[t] = excl;
        cur[t] = excl;
        if (t == NBUCK - 1) bbase[NBUCK] = sh[t];
    }
}

__global__ __launch_bounds__(256) void k_part(const int* __restrict__ src,
                                              const int* __restrict__ dst,
                                              int* __restrict__ cur,
                                              int* __restrict__ packed, int ne) {
    __shared__ int lhist[NBUCK];
    __shared__ int lcur[NBUCK];
    int tid = threadIdx.x;
    for (int i = tid; i < NBUCK; i += 256) lhist[i] = 0;
    __syncthreads();
    int t0 = blockIdx.x * PT_TILE;
    int t1 = t0 + PT_TILE; if (t1 > ne) t1 = ne;
    for (int e = t0 + tid * 4; e < t1; e += 1024) {
        if (e + 3 < t1) {
            int4 d = *(const int4*)(dst + e);
            atomicAdd(&lhist[d.x >> SH], 1);
            atomicAdd(&lhist[d.y >> SH], 1);
            atomicAdd(&lhist[d.z >> SH], 1);
            atomicAdd(&lhist[d.w >> SH], 1);
        } else {
            for (int k = e; k < t1; ++k) atomicAdd(&lhist[dst[k] >> SH], 1);
        }
    }
    __syncthreads();
    for (int i = tid; i < NBUCK; i += 256) {
        int c = lhist[i];
        lcur[i] = c ? atomicAdd(&cur[i], c) : 0;
    }
    __syncthreads();
    for (int e = t0 + tid * 4; e < t1; e += 1024) {
        if (e + 3 < t1) {
            int4 d = *(const int4*)(dst + e);
            int4 s = *(const int4*)(src + e);
            int b, p;
            b = d.x >> SH; p = atomicAdd(&lcur[b], 1); packed[p] = (s.x << SH) | (d.x & (NPB - 1));
            b = d.y >> SH; p = atomicAdd(&lcur[b], 1); packed[p] = (s.y << SH) | (d.y & (NPB - 1));
            b = d.z >> SH; p = atomicAdd(&lcur[b], 1); packed[p] = (s.z << SH) | (d.z & (NPB - 1));
            b = d.w >> SH; p = atomicAdd(&lcur[b], 1); packed[p] = (s.w << SH) | (d.w & (NPB - 1));
        } else {
            for (int k = e; k < t1; ++k) {
                int dd = dst[k], ss = src[k];
                int b = dd >> SH;
                int p = atomicAdd(&lcur[b], 1);
                packed[p] = (ss << SH) | (dd & (NPB - 1));
            }
        }
    }
}

__global__ __launch_bounds__(256) void k_deg(const int* __restrict__ bbase,
                                             const int* __restrict__ packed,
                                             float* __restrict__ dis) {
    __shared__ int cnt[NPB];
    int tid = threadIdx.x, b = blockIdx.x;
    cnt[tid] = 0; cnt[tid + 256] = 0;
    __syncthreads();
    int e0 = bbase[b], e1 = bbase[b + 1];
    for (int e = e0 + tid; e < e1; e += 256)
        atomicAdd(&cnt[packed[e] & (NPB - 1)], 1);
    __syncthreads();
    int i0 = b << SH;
    for (int k = tid; k < NPB; k += 256) {
        int i = i0 + k;
        if (i < NN) dis[i] = rsqrtf((float)cnt[k] + 1.0f);
    }
}

// g1 = half4( dis * (x @ W1) ), wave per row
__global__ __launch_bounds__(256) void k_xw(const float* __restrict__ x,
                                            const float* __restrict__ W1,
                                            const float* __restrict__ dis,
                                            hf4* __restrict__ g, int n) {
    __shared__ float4 sW[128];
    int tid = threadIdx.x;
    if (tid < 128) sW[tid] = ((const float4*)W1)[tid];
    __syncthreads();
    int wave = tid >> 6, lane = tid & 63;
    int row = blockIdx.x * 4 + wave;
    if (row >= n) return;
    float2 xv = ((const float2*)(x + (size_t)row * 128))[lane];
    float4 w0 = sW[2 * lane], w1 = sW[2 * lane + 1];
    float a0 = xv.x * w0.x + xv.y * w1.x;
    float a1 = xv.x * w0.y + xv.y * w1.y;
    float a2 = xv.x * w0.z + xv.y * w1.z;
    float a3 = xv.x * w0.w + xv.y * w1.w;
    for (int off = 32; off; off >>= 1) {
        a0 += __shfl_xor(a0, off);
        a1 += __shfl_xor(a1, off);
        a2 += __shfl_xor(a2, off);
        a3 += __shfl_xor(a3, off);
    }
    if (lane == 0) {
        float dv = dis[row];
        hf4 o;
        o.x = (_Float16)(dv * a0); o.y = (_Float16)(dv * a1);
        o.z = (_Float16)(dv * a2); o.w = (_Float16)(dv * a3);
        g[row] = o;
    }
}

// layer: gin hf4 -> gout hf4 via W (4x4 row-major), bias
__global__ __launch_bounds__(512) void k_agg44(const int* __restrict__ bbase,
                                               const int* __restrict__ packed,
                                               const hf4* __restrict__ gin,
                                               const float* __restrict__ dis,
                                               const float* __restrict__ bias,
                                               const float* __restrict__ W,
                                               hf4* __restrict__ gout) {
    __shared__ float acc[4][NPB];
    int tid = threadIdx.x, b = blockIdx.x;
    for (int k = tid; k < NPB; k += 512) {
        acc[0][k] = 0.f; acc[1][k] = 0.f; acc[2][k] = 0.f; acc[3][k] = 0.f;
    }
    __syncthreads();
    int e0 = bbase[b], e1 = bbase[b + 1];
    for (int e = e0 + tid; e < e1; e += 512) {
        int p = packed[e];
        hf4 gv = gin[p >> SH];
        int nd = p & (NPB - 1);
        unsafeAtomicAdd(&acc[0][nd], (float)gv.x);
        unsafeAtomicAdd(&acc[1][nd], (float)gv.y);
        unsafeAtomicAdd(&acc[2][nd], (float)gv.z);
        unsafeAtomicAdd(&acc[3][nd], (float)gv.w);
    }
    __syncthreads();
    int i0 = b << SH;
    for (int k = tid; k < NPB; k += 512) {
        int i = i0 + k;
        if (i >= NN) continue;
        float dv = dis[i];
        hf4 gs = gin[i];
        float h0 = tanhf(dv * (acc[0][k] + (float)gs.x) + bias[0]);
        float h1 = tanhf(dv * (acc[1][k] + (float)gs.y) + bias[1]);
        float h2 = tanhf(dv * (acc[2][k] + (float)gs.z) + bias[2]);
        float h3 = tanhf(dv * (acc[3][k] + (float)gs.w) + bias[3]);
        hf4 o;
        o.x = (_Float16)(dv * (h0 * W[0] + h1 * W[4] + h2 * W[8]  + h3 * W[12]));
        o.y = (_Float16)(dv * (h0 * W[1] + h1 * W[5] + h2 * W[9]  + h3 * W[13]));
        o.z = (_Float16)(dv * (h0 * W[2] + h1 * W[6] + h2 * W[10] + h3 * W[14]));
        o.w = (_Float16)(dv * (h0 * W[3] + h1 * W[7] + h2 * W[11] + h3 * W[15]));
        gout[i] = o;
    }
}

// layer: gin hf4 -> gout hf2 via W (4x2 row-major), bias
__global__ __launch_bounds__(512) void k_agg42(const int* __restrict__ bbase,
                                               const int* __restrict__ packed,
                                               const hf4* __restrict__ gin,
                                               const float* __restrict__ dis,
                                               const float* __restrict__ bias,
                                               const float* __restrict__ W,
                                               hf2* __restrict__ gout) {
    __shared__ float acc[4][NPB];
    int tid = threadIdx.x, b = blockIdx.x;
    for (int k = tid; k < NPB; k += 512) {
        acc[0][k] = 0.f; acc[1][k] = 0.f; acc[2][k] = 0.f; acc[3][k] = 0.f;
    }
    __syncthreads();
    int e0 = bbase[b], e1 = bbase[b + 1];
    for (int e = e0 + tid; e < e1; e += 512) {
        int p = packed[e];
        hf4 gv = gin[p >> SH];
        int nd = p & (NPB - 1);
        unsafeAtomicAdd(&acc[0][nd], (float)gv.x);
        unsafeAtomicAdd(&acc[1][nd], (float)gv.y);
        unsafeAtomicAdd(&acc[2][nd], (float)gv.z);
        unsafeAtomicAdd(&acc[3][nd], (float)gv.w);
    }
    __syncthreads();
    int i0 = b << SH;
    for (int k = tid; k < NPB; k += 512) {
        int i = i0 + k;
        if (i >= NN) continue;
        float dv = dis[i];
        hf4 gs = gin[i];
        float h0 = tanhf(dv * (acc[0][k] + (float)gs.x) + bias[0]);
        float h1 = tanhf(dv * (acc[1][k] + (float)gs.y) + bias[1]);
        float h2 = tanhf(dv * (acc[2][k] + (float)gs.z) + bias[2]);
        float h3 = tanhf(dv * (acc[3][k] + (float)gs.w) + bias[3]);
        hf2 o;
        o.x = (_Float16)(dv * (h0 * W[0] + h1 * W[2] + h2 * W[4] + h3 * W[6]));
        o.y = (_Float16)(dv * (h0 * W[1] + h1 * W[3] + h2 * W[5] + h3 * W[7]));
        gout[i] = o;
    }
}

// final layer: gin hf2 -> h=tanh(...), out = h@Wc + bc ; writes out f4 + hout f2
__global__ __launch_bounds__(512) void k_agg2out(const int* __restrict__ bbase,
                                                 const int* __restrict__ packed,
                                                 const hf2* __restrict__ gin,
                                                 const float* __restrict__ dis,
                                                 const float* __restrict__ b3,
                                                 const float* __restrict__ Wc,
                                                 const float* __restrict__ bc,
                                                 float4* __restrict__ out,
                                                 float2* __restrict__ hout) {
    __shared__ float acc[2][NPB];
    int tid = threadIdx.x, b = blockIdx.x;
    for (int k = tid; k < NPB; k += 512) { acc[0][k] = 0.f; acc[1][k] = 0.f; }
    __syncthreads();
    int e0 = bbase[b], e1 = bbase[b + 1];
    for (int e = e0 + tid; e < e1; e += 512) {
        int p = packed[e];
        hf2 gv = gin[p >> SH];
        int nd = p & (NPB - 1);
        unsafeAtomicAdd(&acc[0][nd], (float)gv.x);
        unsafeAtomicAdd(&acc[1][nd], (float)gv.y);
    }
    __syncthreads();
    int i0 = b << SH;
    for (int k = tid; k < NPB; k += 512) {
        int i = i0 + k;
        if (i >= NN) continue;
        float dv = dis[i];
        hf2 gs = gin[i];
        float h0 = tanhf(dv * (acc[0][k] + (float)gs.x) + b3[0]);
        float h1 = tanhf(dv * (acc[1][k] + (float)gs.y) + b3[1]);
        float4 o;
        o.x = h0 * Wc[0] + h1 * Wc[4] + bc[0];
        o.y = h0 * Wc[1] + h1 * Wc[5] + bc[1];
        o.z = h0 * Wc[2] + h1 * Wc[6] + bc[2];
        o.w = h0 * Wc[3] + h1 * Wc[7] + bc[3];
        out[i] = o;
        hout[i] = make_float2(h0, h1);
    }
}

extern "C" void kernel_launch(void* const* d_in, const int* in_sizes, int n_in,
                              void* d_out, int out_size, void* d_ws, size_t ws_size,
                              hipStream_t stream) {
    const float* x  = (const float*)d_in[0];
    const int*   ei = (const int*)d_in[1];
    const float* W1 = (const float*)d_in[2];
    const float* b1 = (const float*)d_in[3];
    const float* W2 = (const float*)d_in[4];
    const float* b2 = (const float*)d_in[5];
    const float* W3 = (const float*)d_in[6];
    const float* b3 = (const float*)d_in[7];
    const float* Wc = (const float*)d_in[8];
    const float* bc = (const float*)d_in[9];

    const int n  = NN;
    const int ne = in_sizes[1] / 2;
    const int* src  = ei;
    const int* dstp = ei + ne;

    // workspace (bytes):
    // packed[ne] | dis[n] | g1(hf4)[n] | g2(hf4)[n] | g3(hf2)[n] | bcount | bbase | cur
    char* base = (char*)d_ws;
    int*   packed = (int*)base;                       base += (size_t)ne * 4;
    float* dis    = (float*)base;                     base += (size_t)n * 4;
    hf4*   g1     = (hf4*)base;                       base += (size_t)n * 8;
    hf4*   g2     = (hf4*)base;                       base += (size_t)n * 8;
    hf2*   g3     = (hf2*)base;                       base += (size_t)n * 4;
    int*   bcount = (int*)base;                       base += (NBUCK + 1) * 4;
    int*   bbase  = (int*)base;                       base += (NBUCK + 1) * 4;
    int*   cur    = (int*)base;

    float4* out4  = (float4*)d_out;
    float2* hout2 = (float2*)((float*)d_out + 4 * (size_t)n);

    hipMemsetAsync(bcount, 0, (NBUCK + 1) * 4, stream);
    k_bhist<<<512, 256, 0, stream>>>(dstp, bcount, ne);
    k_bscan<<<1, 1024, 0, stream>>>(bcount, bbase, cur);
    k_part<<<(ne + PT_TILE - 1) / PT_TILE, 256, 0, stream>>>(src, dstp, cur, packed, ne);
    k_deg<<<NBUCK, 256, 0, stream>>>(bbase, packed, dis);
    k_xw<<<(n + 3) / 4, 256, 0, stream>>>(x, W1, dis, g1, n);
    k_agg44<<<NBUCK, 512, 0, stream>>>(bbase, packed, g1, dis, b1, W2, g2);
    k_agg42<<<NBUCK, 512, 0, stream>>>(bbase, packed, g2, dis, b2, W3, g3);
    k_agg2out<<<NBUCK, 512, 0, stream>>>(bbase, packed, g3, dis, b3, Wc, bc,
                                         out4, hout2);
}